// Round 8
// baseline (181.176 us; speedup 1.0000x reference)
//
#include <hip/hip_runtime.h>

// Problem constants (match reference)
constexpr int NUM_LUT = 3;
constexpr int IN_F    = 4096;
constexpr int OUT_F   = 4096;
constexpr int VEC     = 4;
constexpr int LUT     = 16;
constexpr int GROUP   = 128;
constexpr int G       = IN_F / VEC;    // 1024 vector-groups
constexpr int NG      = IN_F / GROUP;  // 32 quant groups

typedef float f32x4 __attribute__((ext_vector_type(4)));

// Persistent pipelined blocks: 8 waves (8 g) each walk 16 consecutive o-tiles
// of 32 o, double-buffering the gate loads in registers across tiles.
constexpr int GT    = 8;                    // g per block (one per wave)
constexpr int OT    = 16;                   // o per wave-pass
constexpr int ITER  = 2;                    // passes per tile -> OB = 32 o
constexpr int OB    = OT * ITER;            // 32
constexpr int BLOCK = 64 * GT;              // 512 threads
constexpr int TILES = 16;                   // o-tiles per block (consecutive)
constexpr int BPR   = (OUT_F / OB) / TILES; // 8 blocks per g-row
constexpr int PAD   = GT * VEC + 4;         // sred row stride: 36 floats

__global__ __launch_bounds__(BLOCK) void recon_kernel(
    const float* __restrict__ gate,      // [3, 1024, 4096, 16]
    const float* __restrict__ codebook,  // [3, 1024, 16, 4]
    const float* __restrict__ scales,    // [4096, 32]
    const int*   __restrict__ zeros,     // [4096, 32]
    float* __restrict__ out)             // [4096, 4096]
{
    __shared__ __align__(16) float cb[NUM_LUT * GT * LUT * VEC]; // 6 KB
    __shared__ __align__(16) float sred[OB][PAD];                // 32 x 36 = 4.5 KB

    const int t    = threadIdx.x;
    const int w    = t >> 6;      // wave id = local g (0..7)
    const int lane = t & 63;
    const int grp  = lane >> 2;   // 4-lane group = local o
    const int c    = lane & 3;    // 16B chunk of the 64B gate row

    const int ob    = blockIdx.x & (BPR - 1);  // o-chunk (fastest)
    const int g0    = (blockIdx.x / BPR) * GT; // g-row
    const int g     = g0 + w;
    const int obase = ob * (TILES * OB);       // 512 consecutive o per block
    const int ng    = g >> 5;

    f32x4 qA[ITER][NUM_LUT], qB[ITER][NUM_LUT];

    // Issue one tile's 6 gate loads (96 B/thread). 1 KB contiguous per
    // instruction per wave; NT keeps the dead stream out of the caches.
    auto issue = [&](f32x4 (&q)[ITER][NUM_LUT], int tt) {
        const int oo = obase + tt * OB;
        #pragma unroll
        for (int i = 0; i < ITER; ++i)
            #pragma unroll
            for (int l = 0; l < NUM_LUT; ++l)
                q[i][l] = __builtin_nontemporal_load(
                    reinterpret_cast<const f32x4*>(
                        gate + ((size_t)(l * G + g) * OUT_F + oo + i * OT) * LUT) + lane);
    };

    auto compute_store = [&](f32x4 (&q)[ITER][NUM_LUT], int tt) {
        const int oo = obase + tt * OB;
        #pragma unroll
        for (int i = 0; i < ITER; ++i) {
            const int o = oo + i * OT + grp;
            float acc = 0.f;
            #pragma unroll
            for (int l = 0; l < NUM_LUT; ++l) {
                const f32x4 v = q[i][l];
                // Local argmax (global idx c*4+j); strict > = first occurrence.
                float bv = v.x; int bi = c * 4;
                if (v.y > bv) { bv = v.y; bi = c * 4 + 1; }
                if (v.z > bv) { bv = v.z; bi = c * 4 + 2; }
                if (v.w > bv) { bv = v.w; bi = c * 4 + 3; }
                // Quad-group merge; ties prefer lower index (jnp.argmax).
                #pragma unroll
                for (int m = 1; m <= 2; m <<= 1) {
                    const float ov = __shfl_xor(bv, m, 64);
                    const int   oi = __shfl_xor(bi, m, 64);
                    if (ov > bv || (ov == bv && oi < bi)) { bv = ov; bi = oi; }
                }
                acc += cb[((l * GT + w) * LUT + bi) * VEC + c];
            }
            const float sc = scales[o * NG + ng];
            const float zp = (float)zeros[o * NG + ng];
            sred[i * OT + grp][w * VEC + c] = (acc - zp) * sc;
        }
        __syncthreads();
        // Store: 256 threads, one f32x4 each; 128B contiguous+aligned per row.
        if (t < OB * GT) {
            const int row = t >> 3, ch = t & 7;
            const f32x4 v = *reinterpret_cast<const f32x4*>(&sred[row][ch * 4]);
            __builtin_nontemporal_store(v, reinterpret_cast<f32x4*>(
                out + (size_t)(oo + row) * IN_F + g0 * VEC + ch * 4));
        }
        __syncthreads();  // protect sred for the next tile
    };

    // Stage codebook once per block (depends only on g0): 384 float4.
    if (t < NUM_LUT * GT * LUT) {
        const int l = t / (GT * LUT), rem = t % (GT * LUT), gl = rem >> 4, s = rem & 15;
        reinterpret_cast<f32x4*>(cb)[t] =
            reinterpret_cast<const f32x4*>(codebook)[(l * G + g0 + gl) * LUT + s];
    }
    issue(qA, 0);        // tile-0 loads in flight across the barrier
    __syncthreads();     // cb visible

    #pragma unroll 1
    for (int tt = 0; tt < TILES; tt += 2) {
        issue(qB, tt + 1);                    // prefetch next tile
        compute_store(qA, tt);                // waits only on qA (counted vmcnt)
        if (tt + 2 < TILES) issue(qA, tt + 2);
        compute_store(qB, tt + 1);
    }
}

extern "C" void kernel_launch(void* const* d_in, const int* in_sizes, int n_in,
                              void* d_out, int out_size, void* d_ws, size_t ws_size,
                              hipStream_t stream) {
    const float* gate     = (const float*)d_in[0];
    const float* codebook = (const float*)d_in[1];
    const float* scales   = (const float*)d_in[2];
    const int*   zeros    = (const int*)d_in[3];
    float*       out      = (float*)d_out;

    const int nblocks = BPR * (G / GT);  // 8 * 128 = 1024 persistent blocks
    recon_kernel<<<nblocks, BLOCK, 0, stream>>>(gate, codebook, scales, zeros, out);
}

// Round 10
// 172.699 us; speedup vs baseline: 1.0491x; 1.0491x over previous
//
#include <hip/hip_runtime.h>

// Problem constants (match reference)
constexpr int NUM_LUT = 3;
constexpr int IN_F    = 4096;
constexpr int OUT_F   = 4096;
constexpr int VEC     = 4;
constexpr int LUT     = 16;
constexpr int GROUP   = 128;
constexpr int G       = IN_F / VEC;    // 1024 vector-groups
constexpr int NG      = IN_F / GROUP;  // 32 quant groups

typedef float f32x4 __attribute__((ext_vector_type(4)));

// 4 lanes per (g,o) pair. Wave = one g x 16 o per iteration.
// Block = 8 waves (8 g) x 4 iterations (64 o) -> output rows get full
// 128B-aligned 128B segments.
constexpr int GT    = 8;    // g per block (one per wave)
constexpr int OT    = 16;   // o per iteration
constexpr int ITER  = 4;    // iterations -> 64 o per block
constexpr int OB    = OT * ITER;
constexpr int BLOCK = 64 * GT;  // 512 threads = 8 waves
constexpr int PAD   = GT * VEC + 4;  // sred row stride: 36 floats

__global__ __launch_bounds__(BLOCK) void recon_kernel(
    const float* __restrict__ gate,      // [3, 1024, 4096, 16]
    const float* __restrict__ codebook,  // [3, 1024, 16, 4]
    const float* __restrict__ scales,    // [4096, 32]
    const int*   __restrict__ zeros,     // [4096, 32]
    float* __restrict__ out)             // [4096, 4096]
{
    __shared__ __align__(16) float cb[NUM_LUT * GT * LUT * VEC]; // 6 KB
    __shared__ __align__(16) float sred[OB][PAD];                // 64 x 36 floats = 9 KB

    const int t    = threadIdx.x;
    const int w    = t >> 6;      // wave id = local g (0..7)
    const int lane = t & 63;
    const int grp  = lane >> 2;   // 4-lane group = local o (within iteration)
    const int c    = lane & 3;    // 16B chunk of the 64B gate row

    const int o0 = blockIdx.x * OB;
    const int g0 = blockIdx.y * GT;
    const int g  = g0 + w;

    // Issue ALL 12 gate loads FIRST (192 B/thread in flight); HBM latency
    // overlaps the codebook staging + barrier. NT loads: every byte is
    // consumed exactly once by exactly one lane.
    f32x4 q[ITER][NUM_LUT];
    #pragma unroll
    for (int i = 0; i < ITER; ++i) {
        #pragma unroll
        for (int l = 0; l < NUM_LUT; ++l) {
            const f32x4* gp = reinterpret_cast<const f32x4*>(
                gate + ((size_t)(l * G + g) * OUT_F + o0 + i * OT) * LUT);
            q[i][l] = __builtin_nontemporal_load(gp + lane);
        }
    }

    // Stage codebook slice: 384 float4 (threads 0..383)
    if (t < NUM_LUT * GT * LUT) {
        const int l = t / (GT * LUT), rem = t % (GT * LUT), gl = rem >> 4, s = rem & 15;
        reinterpret_cast<f32x4*>(cb)[t] =
            reinterpret_cast<const f32x4*>(codebook)[(l * G + g0 + gl) * LUT + s];
    }
    __syncthreads();

    const int ng = g >> 5;  // quant group for columns g*4..g*4+3

    #pragma unroll
    for (int i = 0; i < ITER; ++i) {
        const int o = o0 + i * OT + grp;
        float acc = 0.f;
        #pragma unroll
        for (int l = 0; l < NUM_LUT; ++l) {
            const f32x4 v = q[i][l];
            // Local argmax over this lane's 4 candidates (global idx c*4+j),
            // strict > keeps the first occurrence.
            float bv = v.x; int bi = c * 4;
            if (v.y > bv) { bv = v.y; bi = c * 4 + 1; }
            if (v.z > bv) { bv = v.z; bi = c * 4 + 2; }
            if (v.w > bv) { bv = v.w; bi = c * 4 + 3; }
            // Merge across the 4-lane group; on ties prefer the lower index
            // (= jnp.argmax first-occurrence semantics).
            #pragma unroll
            for (int m = 1; m <= 2; m <<= 1) {
                const float ov = __shfl_xor(bv, m, 64);
                const int   oi = __shfl_xor(bi, m, 64);
                if (ov > bv || (ov == bv && oi < bi)) { bv = ov; bi = oi; }
            }
            acc += cb[((l * GT + w) * LUT + bi) * VEC + c];
        }
        const float sc = scales[o * NG + ng];
        const float zp = (float)zeros[o * NG + ng];
        sred[i * OT + grp][w * VEC + c] = (acc - zp) * sc;
    }
    __syncthreads();

    // Transpose store: 512 threads, one f32x4 each. Row = local o (0..63),
    // 8 chunks x 16B = 128B contiguous, 128B-aligned per row. PLAIN stores:
    // let L2 write-combine the row segments into full bursts (A/B vs R7's
    // nontemporal stores — suspected partial-burst write amplification).
    {
        const int row = t >> 3, ch = t & 7;
        const f32x4 v = *reinterpret_cast<const f32x4*>(&sred[row][ch * 4]);
        *reinterpret_cast<f32x4*>(
            out + (size_t)(o0 + row) * IN_F + g0 * VEC + ch * 4) = v;
    }
}

extern "C" void kernel_launch(void* const* d_in, const int* in_sizes, int n_in,
                              void* d_out, int out_size, void* d_ws, size_t ws_size,
                              hipStream_t stream) {
    const float* gate     = (const float*)d_in[0];
    const float* codebook = (const float*)d_in[1];
    const float* scales   = (const float*)d_in[2];
    const int*   zeros    = (const int*)d_in[3];
    float*       out      = (float*)d_out;

    dim3 grid(OUT_F / OB, G / GT);  // (64, 128) = 8192 blocks, o-tile fastest
    recon_kernel<<<grid, BLOCK, 0, stream>>>(gate, codebook, scales, zeros, out);
}